// Round 1
// baseline (674.180 us; speedup 1.0000x reference)
//
#include <hip/hip_runtime.h>
#include <hip/hip_fp16.h>

// RobustContrastNormalization on [256, 384, 384, 3] fp32.
// Histogram-based quantile (4096 bins over [0,1]) instead of sort.
// Quantile error <= bin width (2.4e-4) -> output error ~3e-4 << 2e-2 threshold.
//
// R1 fix: stats/xg workspace overlap -> hist/stats in module __device__ globals.
// R2 (this round):
//   - Atomic-free histogram merge: each hist block stores its own partial
//     histogram (plain stores); quant_kernel sums HBPS partials. Eliminates
//     ~15M global atomicAdds AND the zero_kernel pass entirely.
//   - NBINS 8192 -> 4096: halves LDS (16 KB -> 10 blocks/CU LDS cap).
//   - xg staged as fp16 (values in [0,1]; rel err 2^-11 -> ~6e-4 output err):
//     saves ~150 MB of HBM round-trip vs fp32 staging.

#define NBINS   4096
#define NPIX    (384 * 384)   // 147456 pixels per sample
#define NSAMP   256
#define HBPS    8             // hist kernel: blocks per sample
#define NBPS    16            // norm kernel: blocks per sample

// Ranks for jnp.quantile linear interpolation, N = 147456:
//   q=0.1: pos = 0.1*(N-1) = 14745.5  -> avg of sorted[14745], sorted[14746]
//   q=0.9: pos = 0.9*(N-1) = 132709.5 -> avg of sorted[132709], sorted[132710]

__device__ unsigned int g_hist[NSAMP * HBPS * NBINS];  // 32 MB partial hists
__device__ float        g_stats[NSAMP * 2];            // lo, 1/rng per sample

__global__ __launch_bounds__(256) void hist_kernel(const float* __restrict__ x,
                                                   __half* __restrict__ xg,
                                                   int writeXg) {
    __shared__ unsigned int lhist[NBINS];
    for (int i = threadIdx.x; i < NBINS; i += 256) lhist[i] = 0u;
    __syncthreads();

    const int s  = blockIdx.x / HBPS;
    const int bs = blockIdx.x % HBPS;
    const int pixPerBlock = NPIX / HBPS;             // 18432
    const long long pixBase = (long long)s * NPIX + (long long)bs * pixPerBlock;
    const float* xp = x + pixBase * 3;
    __half* xgp = xg + pixBase;

    // 256 threads * 4 pixels/thread = 1024 pixels per iteration -> 18 iters.
    for (int it = 0; it < pixPerBlock / 1024; ++it) {
        const int p = it * 1024 + threadIdx.x * 4;   // pixel offset in chunk
        const float4* v = (const float4*)(xp + (long long)p * 3);
        float4 a = v[0], b = v[1], c = v[2];
        const float k3 = 1.0f / 3.0f;
        float m0 = (a.x + a.y + a.z) * k3;
        float m1 = (a.w + b.x + b.y) * k3;
        float m2 = (b.z + b.w + c.x) * k3;
        float m3 = (c.y + c.z + c.w) * k3;
        int i0 = min(NBINS - 1, max(0, (int)(m0 * (float)NBINS)));
        int i1 = min(NBINS - 1, max(0, (int)(m1 * (float)NBINS)));
        int i2 = min(NBINS - 1, max(0, (int)(m2 * (float)NBINS)));
        int i3 = min(NBINS - 1, max(0, (int)(m3 * (float)NBINS)));
        atomicAdd(&lhist[i0], 1u);
        atomicAdd(&lhist[i1], 1u);
        atomicAdd(&lhist[i2], 1u);
        atomicAdd(&lhist[i3], 1u);
        if (writeXg) {
            __half2 h01 = __floats2half2_rn(m0, m1);
            __half2 h23 = __floats2half2_rn(m2, m3);
            uint2 packed;
            packed.x = *(const unsigned int*)&h01;
            packed.y = *(const unsigned int*)&h23;
            *(uint2*)(xgp + p) = packed;
        }
    }
    __syncthreads();

    // Plain stores to this block's private partial histogram (no atomics,
    // no prior zeroing needed -- every bin is overwritten).
    unsigned int* gh = g_hist + ((size_t)s * HBPS + bs) * NBINS;
    for (int i = threadIdx.x; i < NBINS; i += 256) gh[i] = lhist[i];
}

__global__ __launch_bounds__(256) void quant_kernel() {
    const int s = blockIdx.x;
    const unsigned int* gh = g_hist + (size_t)s * HBPS * NBINS;

    __shared__ unsigned int lbh[NBINS];
    __shared__ unsigned int tsum[256];
    __shared__ float results[4];

    // Sum the HBPS partial histograms (coalesced, L3-resident).
    for (int i = threadIdx.x; i < NBINS; i += 256) {
        unsigned int v = 0;
        #pragma unroll
        for (int p = 0; p < HBPS; ++p) v += gh[(size_t)p * NBINS + i];
        lbh[i] = v;
    }
    __syncthreads();

    const int PER  = NBINS / 256;  // 16 bins per thread
    const int base = threadIdx.x * PER;
    unsigned int tot = 0;
    for (int i = 0; i < PER; ++i) tot += lbh[base + i];
    tsum[threadIdx.x] = tot;
    __syncthreads();

    if (threadIdx.x == 0) {
        unsigned int run = 0;
        for (int i = 0; i < 256; ++i) { unsigned int t = tsum[i]; tsum[i] = run; run += t; }
    }
    __syncthreads();

    unsigned int cum = tsum[threadIdx.x];
    const unsigned int ranks[4] = {14745u, 14746u, 132709u, 132710u};
    for (int i = 0; i < PER; ++i) {
        unsigned int c = lbh[base + i];
        if (c) {
            for (int r = 0; r < 4; ++r) {
                unsigned int k = ranks[r];
                if (k >= cum && k < cum + c) {
                    float frac = ((float)(k - cum) + 0.5f) / (float)c;
                    results[r] = ((float)(base + i) + frac) * (1.0f / (float)NBINS);
                }
            }
            cum += c;
        }
    }
    __syncthreads();

    if (threadIdx.x == 0) {
        float lo  = 0.5f * (results[0] + results[1]);
        float hi  = 0.5f * (results[2] + results[3]);
        float rng = fmaxf(hi - lo, 1e-6f);
        g_stats[s * 2 + 0] = lo;
        g_stats[s * 2 + 1] = 1.0f / rng;
    }
}

__global__ __launch_bounds__(256) void norm_kernel(const void* __restrict__ src,
                                                   float* __restrict__ out,
                                                   int fromHalf) {
    const int s  = blockIdx.x / NBPS;
    const int bs = blockIdx.x % NBPS;
    const int pixPerBlock = NPIX / NBPS;             // 9216
    const float lo   = g_stats[s * 2 + 0];
    const float rinv = g_stats[s * 2 + 1];
    const long long pixBase = (long long)s * NPIX + (long long)bs * pixPerBlock;
    float* op = out + pixBase;

    if (fromHalf) {
        const __half* xp = (const __half*)src + pixBase;
        for (int it = 0; it < pixPerBlock / 1024; ++it) {
            const int p = it * 1024 + threadIdx.x * 4;
            uint2 raw = *(const uint2*)(xp + p);
            __half2 h01 = *(const __half2*)&raw.x;
            __half2 h23 = *(const __half2*)&raw.y;
            float2 f01 = __half22float2(h01);
            float2 f23 = __half22float2(h23);
            float4 o;
            o.x = fminf(fmaxf((f01.x - lo) * rinv, 0.0f), 1.0f);
            o.y = fminf(fmaxf((f01.y - lo) * rinv, 0.0f), 1.0f);
            o.z = fminf(fmaxf((f23.x - lo) * rinv, 0.0f), 1.0f);
            o.w = fminf(fmaxf((f23.y - lo) * rinv, 0.0f), 1.0f);
            *(float4*)(op + p) = o;
        }
    } else {
        const float* xp = (const float*)src + pixBase * 3;
        const float k3 = 1.0f / 3.0f;
        for (int it = 0; it < pixPerBlock / 1024; ++it) {
            const int p = it * 1024 + threadIdx.x * 4;
            const float4* v = (const float4*)(xp + (long long)p * 3);
            float4 a = v[0], b = v[1], c = v[2];
            float m0 = (a.x + a.y + a.z) * k3;
            float m1 = (a.w + b.x + b.y) * k3;
            float m2 = (b.z + b.w + c.x) * k3;
            float m3 = (c.y + c.z + c.w) * k3;
            float4 o;
            o.x = fminf(fmaxf((m0 - lo) * rinv, 0.0f), 1.0f);
            o.y = fminf(fmaxf((m1 - lo) * rinv, 0.0f), 1.0f);
            o.z = fminf(fmaxf((m2 - lo) * rinv, 0.0f), 1.0f);
            o.w = fminf(fmaxf((m3 - lo) * rinv, 0.0f), 1.0f);
            *(float4*)(op + p) = o;
        }
    }
}

extern "C" void kernel_launch(void* const* d_in, const int* in_sizes, int n_in,
                              void* d_out, int out_size, void* d_ws, size_t ws_size,
                              hipStream_t stream) {
    const float* x = (const float*)d_in[0];
    float* out = (float*)d_out;

    const size_t xgBytes = (size_t)NSAMP * NPIX * sizeof(__half);  // 75.5 MB
    __half* xg = (__half*)d_ws;
    const int useXg = (ws_size >= xgBytes) ? 1 : 0;

    hist_kernel<<<NSAMP * HBPS, 256, 0, stream>>>(x, xg, useXg);
    quant_kernel<<<NSAMP, 256, 0, stream>>>();
    norm_kernel<<<NSAMP * NBPS, 256, 0, stream>>>(useXg ? (const void*)xg : (const void*)x,
                                                  out, useXg);
}